// Round 7
// baseline (238.686 us; speedup 1.0000x reference)
//
#include <hip/hip_runtime.h>

// ---------------------------------------------------------------------------
// Channel attention (XCA): B=4, N=4096, C=768, H=8, HD=96, fp32 in/out.
// R11: gemm_bt = 128x128 / BK=32 / 4 waves (2x2, per-wave 64x64) / TRIPLE-
// buffered LDS (3 x 16KB = 48KB -> 3 blocks/CU, 12 waves/CU) / ONE barrier
// per K-tile. Per tile t: {ST(t+2 -> buf[(t+2)%3]); RD(buf[t%3]); 16 MFMA;
// VM(4); BAR}. VM(4) forces tile t+1's 4 loads (issued 2 tiles back,
// ~2-phase lead); WAR: ST at t overwrites buf[(t-1)%3], last read t-1,
// separated by BAR(t-1). Stacks intra-block pipelining (R7) WITH inter-
// block overlap (R5/m114, 3 blocks/CU) - the combination all prior rounds
// traded away. Grids: MODE1 12x128=1536 (2 full rounds of 768-concurrent),
// MODE0/2 6x128=768 (1 round).
// ---------------------------------------------------------------------------

using bf16x8 = __attribute__((ext_vector_type(8))) short;
using f32x4  = __attribute__((ext_vector_type(4))) float;

#define SCALE_ 0.10206207261596575f   // 96^-0.5
#define KD 768

__device__ __forceinline__ unsigned short f2bf(float f) {
    unsigned int u = __builtin_bit_cast(unsigned int, f);
    u += 0x7FFFu + ((u >> 16) & 1u);          // RNE, finite inputs only
    return (unsigned short)(u >> 16);
}
__device__ __forceinline__ float bf2f(unsigned short h) {
    unsigned int u = ((unsigned int)h) << 16;
    return __builtin_bit_cast(float, u);
}

__device__ __forceinline__ void glds16(const unsigned short* g, unsigned short* l) {
    __builtin_amdgcn_global_load_lds(
        (const __attribute__((address_space(1))) void*)g,
        (__attribute__((address_space(3))) void*)l, 16, 0, 0);
}

// sum of squares of 8 bf16 packed in a frag
__device__ __forceinline__ float ssq8(bf16x8 v) {
    uint4 u = __builtin_bit_cast(uint4, v);
    unsigned a[4] = {u.x, u.y, u.z, u.w};
    float s = 0.f;
    #pragma unroll
    for (int i = 0; i < 4; i++) {
        float lo = __builtin_bit_cast(float, a[i] << 16);
        float hi = __builtin_bit_cast(float, a[i] & 0xFFFF0000u);
        s += lo * lo + hi * hi;
    }
    return s;
}

// ---------------------------------------------------------------------------
// fp32 -> bf16 bulk convert (memory-bound). 8 elems/thread.
// ---------------------------------------------------------------------------
__global__ void f32_to_bf16_k(const float* __restrict__ in,
                              unsigned short* __restrict__ out)
{
    size_t idx = ((size_t)blockIdx.x * 256 + threadIdx.x) * 8;
    float4 v0 = *(const float4*)&in[idx];
    float4 v1 = *(const float4*)&in[idx + 4];
    unsigned short h[8];
    h[0] = f2bf(v0.x); h[1] = f2bf(v0.y); h[2] = f2bf(v0.z); h[3] = f2bf(v0.w);
    h[4] = f2bf(v1.x); h[5] = f2bf(v1.y); h[6] = f2bf(v1.z); h[7] = f2bf(v1.w);
    *(bf16x8*)&out[idx] = *(bf16x8*)h;
}

// ---------------------------------------------------------------------------
// Weight transpose + fp32->bf16: W[K][N] -> Wt[N][K]. block(32,8).
// ---------------------------------------------------------------------------
__global__ void transpose_to_bf16(const float* __restrict__ W,
                                  unsigned short* __restrict__ Wt,
                                  int K, int N)
{
    __shared__ float tile[32][33];
    int n0 = blockIdx.x * 32, k0 = blockIdx.y * 32;
    int tx = threadIdx.x, ty = threadIdx.y;
    #pragma unroll
    for (int i = 0; i < 32; i += 8)
        tile[ty + i][tx] = W[(size_t)(k0 + ty + i) * N + n0 + tx];
    __syncthreads();
    #pragma unroll
    for (int i = 0; i < 32; i += 8)
        Wt[(size_t)(n0 + ty + i) * K + k0 + tx] = f2bf(tile[tx][ty + i]);
}

// ---------------------------------------------------------------------------
// GEMM: C = A[M][768] * Bt[N][768]^T, bf16. 128x128 block, BK=32, 4 waves
// 2x2, per-wave 64x64 (4x4 frags of 16x16x32 MFMA). Fragment-order 1KB LDS
// blocks (R5-proven): block = row16 holds rows row16*16+(lane&15),
// k = (lane>>4)*8 at lane*16B -> glds16 staging and ds_read_b128 fragment
// reads both lane-sequential (0 bank conflicts). Wave w stages blocks
// w*2, w*2+1 of each operand (2+2 glds16 per K-tile).
// MODE 0: write transposed bf16 Qt[bh][d][n]     (out0)
// MODE 1: cols<768 -> Kt[bh][d][n] (out0); cols>=768 -> Vb[m][768] (out1)
// MODE 2: fp32 + bias row-major (out0)
// ---------------------------------------------------------------------------

#define BAR __builtin_amdgcn_s_barrier()
#define VM(n) asm volatile("s_waitcnt vmcnt(" #n ")" ::: "memory")

#define ST(tt, bi) do { \
    _Pragma("unroll") \
    for (int c_ = 0; c_ < 2; c_++) { \
        glds16(gA + (size_t)(c_ * 16) * KD + (tt) * 32, &As[bi][(w * 2 + c_) * 512]); \
        glds16(gB + (size_t)(c_ * 16) * KD + (tt) * 32, &Bs[bi][(w * 2 + c_) * 512]); \
    } \
} while (0)

template<int MODE>
__global__ __launch_bounds__(256, 3) void gemm_bt(
    const unsigned short* __restrict__ A, const unsigned short* __restrict__ Bt,
    const float* __restrict__ bias, void* __restrict__ out0, void* __restrict__ out1,
    int M, int N)
{
    __shared__ unsigned short As[3][4096];   // 3 x 8KB (8 blocks of 1KB)
    __shared__ unsigned short Bs[3][4096];

    const int Nt = gridDim.x, Mt = gridDim.y;
    const int lin = blockIdx.y * Nt + blockIdx.x;
    const int xcd = lin & 7, li = lin >> 3;
    const int band = Mt >> 3;
    const int mt = xcd * band + (li % band);
    const int nt = li / band;
    const int bm = mt * 128, bn = nt * 128;

    const int t = threadIdx.x, lane = t & 63, w = t >> 6;
    const int mf = lane & 15, quad = lane >> 4;
    const int srow = lane & 15, skc = (lane >> 4) * 8;

    const unsigned short* gA = A  + (size_t)(bm + w * 32 + srow) * KD + skc;
    const unsigned short* gB = Bt + (size_t)(bn + w * 32 + srow) * KD + skc;

    f32x4 acc[4][4] = {};

    // prologue: tiles 0,1 into bufs 0,1 (4 loads each); VM(4) forces tile 0.
    ST(0, 0); ST(1, 1);
    VM(4);
    BAR;

    int cur = 0;
    #pragma unroll 1
    for (int tt = 0; tt < 24; ++tt) {
        int nb = cur - 1; if (nb < 0) nb = 2;     // (tt+2)%3
        if (tt < 22) ST(tt + 2, nb);              // overwrite buf read at tt-1

        bf16x8 a[4], b[4];
        #pragma unroll
        for (int i = 0; i < 4; i++)
            a[i] = *(const bf16x8*)&As[cur][(((w >> 1) * 4) + i) * 512 + lane * 8];
        #pragma unroll
        for (int j = 0; j < 4; j++)
            b[j] = *(const bf16x8*)&Bs[cur][(((w & 1) * 4) + j) * 512 + lane * 8];

        __builtin_amdgcn_s_setprio(1);
        #pragma unroll
        for (int i = 0; i < 4; i++)
            #pragma unroll
            for (int j = 0; j < 4; j++)
                acc[i][j] = __builtin_amdgcn_mfma_f32_16x16x32_bf16(a[i], b[j], acc[i][j], 0, 0, 0);
        __builtin_amdgcn_s_setprio(0);

        if (tt < 22) { VM(4); }                   // tile tt+1 (issued tt-1) done
        else if (tt == 22) { VM(0); }             // tile 23 done
        BAR;
        cur = cur + 1; if (cur == 3) cur = 0;
    }

    // C/D layout: col = lane&15, row = quad*4 + r
    if constexpr (MODE == 2) {
        float* C = (float*)out0;
        #pragma unroll
        for (int i = 0; i < 4; i++) {
            int row0 = bm + (w >> 1) * 64 + i * 16 + quad * 4;
            #pragma unroll
            for (int j = 0; j < 4; j++) {
                int col = bn + (w & 1) * 64 + j * 16 + mf;
                float bv = bias[col];
                #pragma unroll
                for (int r = 0; r < 4; r++)
                    C[(size_t)(row0 + r) * N + col] = acc[i][j][r] + bv;
            }
        }
    } else {
        unsigned short* Tr = (unsigned short*)out0;   // Qt or Kt [bh][96][4096]
        unsigned short* Vb = (unsigned short*)out1;   // [16384][768]
        const bool kpart = (MODE == 0) || (bn < 768); // uniform (bn mult of 128)
        #pragma unroll
        for (int i = 0; i < 4; i++) {
            int row0 = bm + (w >> 1) * 64 + i * 16 + quad * 4;  // token index
            int bb = row0 >> 12, n = row0 & 4095;
            #pragma unroll
            for (int j = 0; j < 4; j++) {
                int c = bn + (w & 1) * 64 + j * 16 + mf;
                if (kpart) {
                    int h = (c * 683) >> 16;          // floor(c/96) for c<768
                    int d = c - h * 96;
                    size_t o = ((size_t)((bb * 8 + h) * 96 + d)) * 4096 + n;
                    ushort4 v4;
                    v4.x = f2bf(acc[i][j][0]); v4.y = f2bf(acc[i][j][1]);
                    v4.z = f2bf(acc[i][j][2]); v4.w = f2bf(acc[i][j][3]);
                    *(ushort4*)&Tr[o] = v4;
                } else {
                    int cv = c - 768;
                    #pragma unroll
                    for (int r = 0; r < 4; r++)
                        Vb[(size_t)(row0 + r) * 768 + cv] = f2bf(acc[i][j][r]);
                }
            }
        }
    }
}

#undef ST
#undef VM
#undef BAR

// ---------------------------------------------------------------------------
// S-gram: Spart[bh][s][96][96] = sum over 512-n window of Qt[d][n]*Kt[e][n].
// ---------------------------------------------------------------------------
__global__ __launch_bounds__(256) void s_gemm(
    const unsigned short* __restrict__ Qt, const unsigned short* __restrict__ Kt,
    float* __restrict__ Spart, float* __restrict__ ssq)
{
    __shared__ unsigned short Qs[2][12 * 512];
    __shared__ unsigned short Ks[2][12 * 512];
    const int s = blockIdx.x, bh = blockIdx.y;
    const int t = threadIdx.x, lane = t & 63, w = t >> 6;
    const int m0 = (w >> 1) * 48, n0w = (w & 1) * 48;
    const int mf = lane & 15, quad = lane >> 4;
    const int srow = lane & 15, skc = (lane >> 4) * 8;
    const int nwin = s * 512;

    const unsigned short* Qg = Qt + (size_t)bh * 96 * 4096;
    const unsigned short* Kg = Kt + (size_t)bh * 96 * 4096;

    f32x4 acc[3][3] = {};
    float sq[3] = {0.f, 0.f, 0.f}, sk[3] = {0.f, 0.f, 0.f};

    #pragma unroll
    for (int c = 0; c < 3; c++) {
        int bi = w * 3 + c, kc = bi / 6, g = bi % 6;
        size_t go = (size_t)(g * 16 + srow) * 4096 + nwin + kc * 32 + skc;
        glds16(Qg + go, &Qs[0][bi * 512]);
        glds16(Kg + go, &Ks[0][bi * 512]);
    }

    for (int it = 0; it < 8; it++) {
        const int cur = it & 1;
        __syncthreads();
        if (it + 1 < 8) {
            const int nxt = cur ^ 1;
            const int nn = nwin + (it + 1) * 64;
            #pragma unroll
            for (int c = 0; c < 3; c++) {
                int bi = w * 3 + c, kc = bi / 6, g = bi % 6;
                size_t go = (size_t)(g * 16 + srow) * 4096 + nn + kc * 32 + skc;
                glds16(Qg + go, &Qs[nxt][bi * 512]);
                glds16(Kg + go, &Ks[nxt][bi * 512]);
            }
        }
        #pragma unroll
        for (int kk = 0; kk < 2; kk++) {
            bf16x8 a[3], b[3];
            #pragma unroll
            for (int i = 0; i < 3; i++)
                a[i] = *(const bf16x8*)&Qs[cur][(kk * 6 + (w >> 1) * 3 + i) * 512 + lane * 8];
            #pragma unroll
            for (int j = 0; j < 3; j++)
                b[j] = *(const bf16x8*)&Ks[cur][(kk * 6 + (w & 1) * 3 + j) * 512 + lane * 8];
            if ((w & 1) == 0) {
                #pragma unroll
                for (int i = 0; i < 3; i++) sq[i] += ssq8(a[i]);
            }
            if ((w >> 1) == 0) {
                #pragma unroll
                for (int j = 0; j < 3; j++) sk[j] += ssq8(b[j]);
            }
            #pragma unroll
            for (int i = 0; i < 3; i++)
                #pragma unroll
                for (int j = 0; j < 3; j++)
                    acc[i][j] = __builtin_amdgcn_mfma_f32_16x16x32_bf16(a[i], b[j], acc[i][j], 0, 0, 0);
        }
    }

    if ((w & 1) == 0) {
        #pragma unroll
        for (int i = 0; i < 3; i++) {
            float v = sq[i];
            v += __shfl_xor(v, 16, 64);
            v += __shfl_xor(v, 32, 64);
            if (lane < 16) atomicAdd(&ssq[bh * 96 + m0 + i * 16 + lane], v);
        }
    }
    if ((w >> 1) == 0) {
        #pragma unroll
        for (int j = 0; j < 3; j++) {
            float v = sk[j];
            v += __shfl_xor(v, 16, 64);
            v += __shfl_xor(v, 32, 64);
            if (lane < 16) atomicAdd(&ssq[3072 + bh * 96 + n0w + j * 16 + lane], v);
        }
    }

    float* outp = Spart + (size_t)(bh * 8 + s) * 9216;
    #pragma unroll
    for (int i = 0; i < 3; i++)
        #pragma unroll
        for (int j = 0; j < 3; j++) {
            int e  = n0w + j * 16 + mf;
            int d0 = m0 + i * 16 + quad * 4;
            #pragma unroll
            for (int r = 0; r < 4; r++)
                outp[(d0 + r) * 96 + e] = acc[i][j][r];
        }
}

// ---------------------------------------------------------------------------
// Softmax, wave-per-row: grid(24, 32bh) x 256 thr.
// ---------------------------------------------------------------------------
__global__ __launch_bounds__(256) void softmax_k(
    const float* __restrict__ Spart, const float* __restrict__ ssq,
    unsigned short* __restrict__ P)
{
    const int bh = blockIdx.y;
    const int d  = blockIdx.x * 4 + (threadIdx.x >> 6);
    const int lane = threadIdx.x & 63;

    const float sr = SCALE_ / fmaxf(sqrtf(ssq[bh * 96 + d]), 1e-12f);

    const float* Sp = Spart + (size_t)bh * 8 * 9216 + d * 96;
    float sa = 0.f, sb = 0.f;
    #pragma unroll
    for (int ch = 0; ch < 8; ch++) {
        sa += Sp[ch * 9216 + lane];
        if (lane < 32) sb += Sp[ch * 9216 + 64 + lane];
    }
    float ka = 1.0f / fmaxf(sqrtf(ssq[3072 + bh * 96 + lane]), 1e-12f);
    float va = sa * sr * ka;
    float vb = -1e30f;
    if (lane < 32) {
        float kb = 1.0f / fmaxf(sqrtf(ssq[3072 + bh * 96 + 64 + lane]), 1e-12f);
        vb = sb * sr * kb;
    }

    float m = fmaxf(va, vb);
    #pragma unroll
    for (int off = 32; off >= 1; off >>= 1)
        m = fmaxf(m, __shfl_xor(m, off, 64));

    float ea = __expf(va - m);
    float eb = (lane < 32) ? __expf(vb - m) : 0.f;
    float ssum = ea + eb;
    #pragma unroll
    for (int off = 32; off >= 1; off >>= 1)
        ssum += __shfl_xor(ssum, off, 64);

    float inv = 1.0f / ssum;
    unsigned short* Pr = P + (size_t)bh * 9216 + d * 96;
    Pr[lane] = f2bf(ea * inv);
    if (lane < 32) Pr[64 + lane] = f2bf(eb * inv);
}

// ---------------------------------------------------------------------------
// x[n][d] = sum_e V[n][e] * P[d][e] per (b,h). V from compact Vb[m][768].
// ---------------------------------------------------------------------------
__global__ __launch_bounds__(256) void pv_gemm(
    const unsigned short* __restrict__ Vb, const unsigned short* __restrict__ P,
    unsigned short* __restrict__ X)
{
    __shared__ unsigned short Ps[96][104];
    int ntile = blockIdx.x, bh = blockIdx.y;
    int b = bh >> 3, h = bh & 7;
    int t = threadIdx.x, lane = t & 63, w = t >> 6;

    const unsigned short* Pg = P + (size_t)bh * 9216;
    #pragma unroll
    for (int i = 0; i < 9; i++) {
        int idx4 = t + 256 * i;
        int row = idx4 / 24, c4 = (idx4 - row * 24) * 4;
        *(ushort4*)&Ps[row][c4] = *(const ushort4*)&Pg[row * 96 + c4];
    }
    __syncthreads();

    const unsigned short* Vbase = Vb + (size_t)b * 4096 * 768 + h * 96;
    int mf = lane & 15, k8 = (lane >> 4) * 8;
    f32x4 acc[2][6] = {};
    #pragma unroll
    for (int k = 0; k < 3; k++) {
        bf16x8 a[2], bb[6];
        #pragma unroll
        for (int i = 0; i < 2; i++) {
            int row = ntile * 128 + w * 32 + i * 16 + mf;
            a[i] = *(const bf16x8*)&Vbase[(size_t)row * 768 + k * 32 + k8];
        }
        #pragma unroll
        for (int j = 0; j < 6; j++)
            bb[j] = *(const bf16x8*)&Ps[j * 16 + mf][k * 32 + k8];
        #pragma unroll
        for (int i = 0; i < 2; i++)
            #pragma unroll
            for (int j = 0; j < 6; j++)
                acc[i][j] = __builtin_amdgcn_mfma_f32_16x16x32_bf16(a[i], bb[j], acc[i][j], 0, 0, 0);
    }
    #pragma unroll
    for (int i = 0; i < 2; i++)
        #pragma unroll
        for (int j = 0; j < 6; j++)
            #pragma unroll
            for (int r = 0; r < 4; r++) {
                int n_tok = ntile * 128 + w * 32 + i * 16 + (lane >> 4) * 4 + r;
                int c = h * 96 + j * 16 + mf;
                X[((size_t)b * 4096 + n_tok) * 768 + c] = f2bf(acc[i][j][r]);
            }
}

// ---------------------------------------------------------------------------
extern "C" void kernel_launch(void* const* d_in, const int* in_sizes, int n_in,
                              void* d_out, int out_size, void* d_ws, size_t ws_size,
                              hipStream_t stream)
{
    (void)in_sizes; (void)n_in; (void)out_size; (void)ws_size;
    const float* ctx   = (const float*)d_in[0];
    const float* dep   = (const float*)d_in[1];
    const float* Wq    = (const float*)d_in[2];
    const float* Wkv   = (const float*)d_in[3];
    const float* Wproj = (const float*)d_in[4];
    const float* bproj = (const float*)d_in[5];
    float* out = (float*)d_out;

    char* p = (char*)d_ws;
    auto carve = [&](size_t bytes) {
        char* r = p;
        p += (bytes + 255) & ~(size_t)255;
        return r;
    };
    unsigned short* WqT    = (unsigned short*)carve((size_t)768 * 768 * 2);
    unsigned short* WkvT   = (unsigned short*)carve((size_t)1536 * 768 * 2);
    unsigned short* WprojT = (unsigned short*)carve((size_t)768 * 768 * 2);
    unsigned short* Qt     = (unsigned short*)carve((size_t)32 * 96 * 4096 * 2);
    unsigned short* Kt     = (unsigned short*)carve((size_t)32 * 96 * 4096 * 2);
    unsigned short* Vb     = (unsigned short*)carve((size_t)16384 * 768 * 2);
    unsigned short* Xb     = (unsigned short*)carve((size_t)16384 * 768 * 2);
    float*          ssq    = (float*)carve((size_t)2 * 3072 * 4);
    float*          Spart  = (float*)carve((size_t)32 * 8 * 9216 * 4);
    unsigned short* Pb     = (unsigned short*)carve((size_t)32 * 9216 * 2);
    unsigned short* depB   = (unsigned short*)carve((size_t)16384 * 768 * 2);
    // ctx-bf16 aliases Xb: Q-gemm consumes it before pv_gemm writes Xb.
    unsigned short* ctxB   = Xb;

    hipMemsetAsync(ssq, 0, 2 * 3072 * 4, stream);

    f32_to_bf16_k<<<6144, 256, 0, stream>>>(ctx, ctxB);
    f32_to_bf16_k<<<6144, 256, 0, stream>>>(dep, depB);

    dim3 tb(32, 8);
    transpose_to_bf16<<<dim3(24, 24), tb, 0, stream>>>(Wq, WqT, 768, 768);
    transpose_to_bf16<<<dim3(48, 24), tb, 0, stream>>>(Wkv, WkvT, 768, 1536);
    transpose_to_bf16<<<dim3(24, 24), tb, 0, stream>>>(Wproj, WprojT, 768, 768);

    gemm_bt<0><<<dim3(6, 128), 256, 0, stream>>>(ctxB, WqT, nullptr, Qt, nullptr, 16384, 768);
    gemm_bt<1><<<dim3(12, 128), 256, 0, stream>>>(depB, WkvT, nullptr, Kt, Vb, 16384, 1536);

    s_gemm<<<dim3(8, 32), 256, 0, stream>>>(Qt, Kt, Spart, ssq);
    softmax_k<<<dim3(24, 32), 256, 0, stream>>>(Spart, ssq, Pb);
    pv_gemm<<<dim3(32, 32), 256, 0, stream>>>(Vb, Pb, Xb);
    gemm_bt<2><<<dim3(6, 128), 256, 0, stream>>>(Xb, WprojT, bproj, out, nullptr, 16384, 768);
}